// Round 3
// baseline (543.458 us; speedup 1.0000x reference)
//
#include <hip/hip_runtime.h>
#include <hip/hip_bf16.h>

// All float tensors are fp32 per the reference (jnp.float32 everywhere).
// Intermediate message matrix `t` is stored bf16 (error ~1e-3 << 1.56e-2
// threshold) to halve scatter gather traffic and keep ws at ~19.6 MB.

// ---------------- kernel 1: out-degree count over row ----------------
__global__ __launch_bounds__(256) void k_deg(const int* __restrict__ row,
                                             int* __restrict__ deg, int E) {
  int e = blockIdx.x * blockDim.x + threadIdx.x;
  if (e < E) atomicAdd(&deg[row[e]], 1);
}

// ---------------- kernel 2: dinv = deg > 0 ? deg^-1/2 : 0 ----------------
__global__ __launch_bounds__(256) void k_dinv(const int* __restrict__ deg,
                                              float* __restrict__ dinv, int N) {
  int i = blockIdx.x * blockDim.x + threadIdx.x;
  if (i < N) {
    int d = deg[i];
    dinv[i] = (d > 0) ? (1.0f / sqrtf((float)d)) : 0.0f;
  }
}

// ---------------- dual GEMM: t = h@Wn (bf16 out), agg = h@Wi + bias ----------------
// h: [N,64] fp32 (optional relu-on-load), Wn/Wi: [64,64] fp32.
// NOTE: h and agg may ALIAS (in-place layer 2). Safe because each block only
// touches rows [64b,64b+64), reads each 16-row group into LDS before writing
// it, and never re-reads rows it has written. No __restrict__ on h/agg.
template <bool RELU>
__global__ __launch_bounds__(256) void k_dual_gemm(
    const float* h,
    const float* __restrict__ Wn,
    const float* __restrict__ Wi,
    const float* __restrict__ bias,
    __hip_bfloat16* __restrict__ t, float* agg, int N) {
  __shared__ float Wn_s[64 * 64];
  __shared__ float Wi_s[64 * 64];
  __shared__ float b_s[64];
  __shared__ float h_s[16 * 64];

  const int tid = threadIdx.x;
  for (int i = tid; i < 4096; i += 256) {
    Wn_s[i] = Wn[i];
    Wi_s[i] = Wi[i];
  }
  if (tid < 64) b_s[tid] = bias[tid];

  const int j = tid & 63;      // output column
  const int quad = tid >> 6;   // wave id 0..3
  const int r0 = blockIdx.x * 64;

  for (int g = 0; g < 4; ++g) {
    __syncthreads();  // protects h_s from prior readers; fences weight staging (g=0)
#pragma unroll
    for (int i = 0; i < 4; ++i) {
      int idx = tid + i * 256;        // 0..1023
      int rr = idx >> 6;              // 0..15
      int cc = idx & 63;
      int rload = r0 + g * 16 + rr;
      float v = 0.0f;
      if (rload < N) {
        float xv = h[(size_t)rload * 64 + cc];
        v = RELU ? fmaxf(xv, 0.0f) : xv;
      }
      h_s[idx] = v;
    }
    __syncthreads();

    float acc_t[4] = {0.f, 0.f, 0.f, 0.f};
    float acc_a[4] = {0.f, 0.f, 0.f, 0.f};
#pragma unroll 8
    for (int k = 0; k < 64; ++k) {
      float wn = Wn_s[k * 64 + j];
      float wi = Wi_s[k * 64 + j];
#pragma unroll
      for (int rr = 0; rr < 4; ++rr) {
        float hk = h_s[(quad * 4 + rr) * 64 + k];
        acc_t[rr] = fmaf(hk, wn, acc_t[rr]);
        acc_a[rr] = fmaf(hk, wi, acc_a[rr]);
      }
    }
#pragma unroll
    for (int rr = 0; rr < 4; ++rr) {
      int r = r0 + g * 16 + quad * 4 + rr;
      if (r < N) {
        t[(size_t)r * 64 + j] = __float2bfloat16(acc_t[rr]);
        agg[(size_t)r * 64 + j] = acc_a[rr] + b_s[j];
      }
    }
  }
}

// ---------------- edge scatter: agg[col] += t[row] * norm ----------------
// One 64-lane wave per edge; lane = feature index.
__global__ __launch_bounds__(256) void k_scatter(
    const int* __restrict__ row, const int* __restrict__ col,
    const float* __restrict__ dinv, const __hip_bfloat16* __restrict__ t,
    float* __restrict__ agg, int E) {
  int e = blockIdx.x * 4 + (threadIdx.x >> 6);
  int lane = threadIdx.x & 63;
  if (e >= E) return;
  int r = row[e];
  int c = col[e];
  float nrm = dinv[r] * dinv[c];
  float v = __bfloat162float(t[(size_t)r * 64 + lane]) * nrm;
  unsafeAtomicAdd(&agg[(size_t)c * 64 + lane], v);
}

// ---------------- output GEMM: out = relu(h) @ Wo + bo (fp32 out) ----------------
__global__ __launch_bounds__(256) void k_out_gemm(
    const float* __restrict__ h,
    const float* __restrict__ Wo,   // [64,32]
    const float* __restrict__ bo,   // [32]
    float* __restrict__ out, int N) {
  __shared__ float Wo_s[64 * 32];
  __shared__ float bo_s[32];
  __shared__ float h_s[16 * 64];

  const int tid = threadIdx.x;
  for (int i = tid; i < 2048; i += 256) Wo_s[i] = Wo[i];
  if (tid < 32) bo_s[tid] = bo[tid];

  const int j = tid & 31;       // output column
  const int rsub = tid >> 5;    // 0..7
  const int r0 = blockIdx.x * 64;

  for (int g = 0; g < 4; ++g) {
    __syncthreads();
#pragma unroll
    for (int i = 0; i < 4; ++i) {
      int idx = tid + i * 256;
      int rr = idx >> 6;
      int cc = idx & 63;
      int rload = r0 + g * 16 + rr;
      float v = 0.0f;
      if (rload < N) v = fmaxf(h[(size_t)rload * 64 + cc], 0.0f);
      h_s[idx] = v;
    }
    __syncthreads();
#pragma unroll
    for (int rh = 0; rh < 2; ++rh) {
      int rloc = rsub + rh * 8;
      float acc = 0.0f;
#pragma unroll 8
      for (int k = 0; k < 64; ++k)
        acc = fmaf(h_s[rloc * 64 + k], Wo_s[k * 32 + j], acc);
      int r = r0 + g * 16 + rloc;
      if (r < N) out[(size_t)r * 32 + j] = acc + bo_s[j];
    }
  }
}

extern "C" void kernel_launch(void* const* d_in, const int* in_sizes, int n_in,
                              void* d_out, int out_size, void* d_ws, size_t ws_size,
                              hipStream_t stream) {
  const float* x = (const float*)d_in[0];
  const int* ei = (const int*)d_in[1];
  const float* W_in1 = (const float*)d_in[2];
  const float* W_neigh1 = (const float*)d_in[3];
  const float* bias1 = (const float*)d_in[4];
  const float* W_in2 = (const float*)d_in[5];
  const float* W_neigh2 = (const float*)d_in[6];
  const float* bias2 = (const float*)d_in[7];
  const float* W_out = (const float*)d_in[8];
  const float* b_out = (const float*)d_in[9];
  float* out = (float*)d_out;

  const int N = in_sizes[0] / 64;
  const int E = in_sizes[1] / 2;
  const int* row = ei;       // edge_index[0] = sources
  const int* col = ei + E;   // edge_index[1] = targets

  // workspace carve-up (256B aligned): deg, dinv, t(bf16), agg(fp32, reused
  // in-place for both layers). Total ~19.6 MB.
  char* ws = (char*)d_ws;
  size_t off = 0;
  auto alloc = [&](size_t bytes) -> void* {
    void* p = ws + off;
    off += (bytes + 255) & ~(size_t)255;
    return p;
  };
  int* deg = (int*)alloc((size_t)N * 4);
  float* dinv = (float*)alloc((size_t)N * 4);
  __hip_bfloat16* t = (__hip_bfloat16*)alloc((size_t)N * 64 * 2);
  float* agg = (float*)alloc((size_t)N * 64 * 4);
  (void)ws_size;

  hipMemsetAsync(deg, 0, (size_t)N * 4, stream);

  int gE = (E + 255) / 256;
  int gN = (N + 255) / 256;
  int gRows = (N + 63) / 64;
  int gEdge = (E + 3) / 4;

  k_deg<<<gE, 256, 0, stream>>>(row, deg, E);
  k_dinv<<<gN, 256, 0, stream>>>(deg, dinv, N);

  // layer 1: t = x@W_neigh1, agg = x@W_in1 + bias1
  k_dual_gemm<false><<<gRows, 256, 0, stream>>>(
      x, W_neigh1, W_in1, bias1, t, agg, N);
  k_scatter<<<gEdge, 256, 0, stream>>>(row, col, dinv, t, agg, E);

  // layer 2 (relu on load, IN-PLACE on agg):
  // t = relu(agg)@W_neigh2, agg = relu(agg)@W_in2 + bias2
  k_dual_gemm<true><<<gRows, 256, 0, stream>>>(
      agg, W_neigh2, W_in2, bias2, t, agg, N);
  k_scatter<<<gEdge, 256, 0, stream>>>(row, col, dinv, t, agg, E);

  // output: out = relu(agg)@W_out + b_out
  k_out_gemm<<<gRows, 256, 0, stream>>>(agg, W_out, b_out, out, N);
}

// Round 4
// 353.692 us; speedup vs baseline: 1.5365x; 1.5365x over previous
//
#include <hip/hip_runtime.h>
#include <hip/hip_bf16.h>

// All float tensors are fp32 per the reference. Intermediate message matrix
// `t` stored bf16 (absmax contribution ~4e-3 << 1.56e-2 threshold, halves
// gather traffic). Aggregation is CSR-gather (no float atomics): round-3
// profile showed fp32 atomic adds write through to HBM (WRITE_SIZE == full
// 200 MB atomic traffic) at 175 us/scatter.

// ---------- degrees: out-degree over row (norm) + in-degree over col (CSR) ----------
__global__ __launch_bounds__(256) void k_degrees(const int* __restrict__ row,
                                                 const int* __restrict__ col,
                                                 int* __restrict__ deg,
                                                 int* __restrict__ indeg, int E) {
  int e = blockIdx.x * blockDim.x + threadIdx.x;
  if (e < E) {
    atomicAdd(&deg[row[e]], 1);
    atomicAdd(&indeg[col[e]], 1);
  }
}

// ---------- dinv = deg > 0 ? deg^-1/2 : 0 ----------
__global__ __launch_bounds__(256) void k_dinv(const int* __restrict__ deg,
                                              float* __restrict__ dinv, int N) {
  int i = blockIdx.x * blockDim.x + threadIdx.x;
  if (i < N) {
    int d = deg[i];
    dinv[i] = (d > 0) ? (1.0f / sqrtf((float)d)) : 0.0f;
  }
}

// ---------- exclusive scan of indeg -> ptr (3-kernel hierarchical) ----------
__global__ __launch_bounds__(1024) void k_scan1(const int* __restrict__ in,
                                                int* __restrict__ out,
                                                int* __restrict__ bsum, int n) {
  __shared__ int s[1024];
  int g = blockIdx.x * 1024 + threadIdx.x;
  int v = (g < n) ? in[g] : 0;
  s[threadIdx.x] = v;
  __syncthreads();
  for (int off = 1; off < 1024; off <<= 1) {
    int tv = (threadIdx.x >= off) ? s[threadIdx.x - off] : 0;
    __syncthreads();
    s[threadIdx.x] += tv;
    __syncthreads();
  }
  if (g < n) out[g] = s[threadIdx.x] - v;  // exclusive
  if (threadIdx.x == 1023) bsum[blockIdx.x] = s[1023];
}

__global__ void k_scan2(int* __restrict__ bsum, int nb) {
  if (threadIdx.x == 0 && blockIdx.x == 0) {
    int acc = 0;
    for (int i = 0; i < nb; ++i) { int v = bsum[i]; bsum[i] = acc; acc += v; }
  }
}

__global__ __launch_bounds__(1024) void k_scan3(int* __restrict__ out,
                                                const int* __restrict__ bsum, int n) {
  int g = blockIdx.x * 1024 + threadIdx.x;
  if (g < n) out[g] += bsum[blockIdx.x];
}

// ---------- bin edges into CSR (int atomics on 200 KB ptr array) ----------
// After this kernel ptr[c] == segment END (exclusive-scan value + indeg),
// so gather recovers start = ptr[c] - indeg[c]. Bin once, gather twice.
__global__ __launch_bounds__(256) void k_bin(const int* __restrict__ row,
                                             const int* __restrict__ col,
                                             int* __restrict__ ptr,
                                             int* __restrict__ csr_row, int E) {
  int e = blockIdx.x * blockDim.x + threadIdx.x;
  if (e < E) {
    int pos = atomicAdd(&ptr[col[e]], 1);
    csr_row[pos] = row[e];
  }
}

// ---------- dual GEMM: t = h@Wn (bf16 out), agg = h@Wi + bias ----------
// h and agg may ALIAS (in-place layer 2): each block touches only rows
// [64b,64b+64), stages each 16-row group into LDS before overwriting it.
template <bool RELU>
__global__ __launch_bounds__(256) void k_dual_gemm(
    const float* h,
    const float* __restrict__ Wn,
    const float* __restrict__ Wi,
    const float* __restrict__ bias,
    __hip_bfloat16* __restrict__ t, float* agg, int N) {
  __shared__ float Wn_s[64 * 64];
  __shared__ float Wi_s[64 * 64];
  __shared__ float b_s[64];
  __shared__ float h_s[16 * 64];

  const int tid = threadIdx.x;
  for (int i = tid; i < 4096; i += 256) {
    Wn_s[i] = Wn[i];
    Wi_s[i] = Wi[i];
  }
  if (tid < 64) b_s[tid] = bias[tid];

  const int j = tid & 63;
  const int quad = tid >> 6;
  const int r0 = blockIdx.x * 64;

  for (int g = 0; g < 4; ++g) {
    __syncthreads();
#pragma unroll
    for (int i = 0; i < 4; ++i) {
      int idx = tid + i * 256;
      int rr = idx >> 6;
      int cc = idx & 63;
      int rload = r0 + g * 16 + rr;
      float v = 0.0f;
      if (rload < N) {
        float xv = h[(size_t)rload * 64 + cc];
        v = RELU ? fmaxf(xv, 0.0f) : xv;
      }
      h_s[idx] = v;
    }
    __syncthreads();

    float acc_t[4] = {0.f, 0.f, 0.f, 0.f};
    float acc_a[4] = {0.f, 0.f, 0.f, 0.f};
#pragma unroll 8
    for (int k = 0; k < 64; ++k) {
      float wn = Wn_s[k * 64 + j];
      float wi = Wi_s[k * 64 + j];
#pragma unroll
      for (int rr = 0; rr < 4; ++rr) {
        float hk = h_s[(quad * 4 + rr) * 64 + k];
        acc_t[rr] = fmaf(hk, wn, acc_t[rr]);
        acc_a[rr] = fmaf(hk, wi, acc_a[rr]);
      }
    }
#pragma unroll
    for (int rr = 0; rr < 4; ++rr) {
      int r = r0 + g * 16 + quad * 4 + rr;
      if (r < N) {
        t[(size_t)r * 64 + j] = __float2bfloat16(acc_t[rr]);
        agg[(size_t)r * 64 + j] = acc_a[rr] + b_s[j];
      }
    }
  }
}

// ---------- CSR gather: agg[n] += sum_e t[row_e] * dinv[row_e]*dinv[n] ----------
// One 64-lane wave per node, lane = feature. No atomics.
__global__ __launch_bounds__(256) void k_gather(
    const int* __restrict__ csr_row, const int* __restrict__ ptr,
    const int* __restrict__ indeg, const float* __restrict__ dinv,
    const __hip_bfloat16* __restrict__ t, float* __restrict__ agg, int N) {
  int n = blockIdx.x * 4 + (threadIdx.x >> 6);
  if (n >= N) return;
  int lane = threadIdx.x & 63;
  int end = ptr[n];           // after k_bin, ptr[n] == segment end
  int dg = indeg[n];
  int i = end - dg;
  float dn = dinv[n];
  float acc = agg[(size_t)n * 64 + lane];

  for (; i + 4 <= end; i += 4) {
    int r0 = csr_row[i], r1 = csr_row[i + 1], r2 = csr_row[i + 2], r3 = csr_row[i + 3];
    float v0 = __bfloat162float(t[(size_t)r0 * 64 + lane]);
    float v1 = __bfloat162float(t[(size_t)r1 * 64 + lane]);
    float v2 = __bfloat162float(t[(size_t)r2 * 64 + lane]);
    float v3 = __bfloat162float(t[(size_t)r3 * 64 + lane]);
    float n0 = dinv[r0] * dn, n1 = dinv[r1] * dn, n2 = dinv[r2] * dn, n3 = dinv[r3] * dn;
    acc = fmaf(v0, n0, acc);
    acc = fmaf(v1, n1, acc);
    acc = fmaf(v2, n2, acc);
    acc = fmaf(v3, n3, acc);
  }
  for (; i < end; ++i) {
    int r = csr_row[i];
    acc = fmaf(__bfloat162float(t[(size_t)r * 64 + lane]), dinv[r] * dn, acc);
  }
  agg[(size_t)n * 64 + lane] = acc;
}

// ---------- output GEMM: out = relu(h) @ Wo + bo ----------
__global__ __launch_bounds__(256) void k_out_gemm(
    const float* __restrict__ h,
    const float* __restrict__ Wo,   // [64,32]
    const float* __restrict__ bo,   // [32]
    float* __restrict__ out, int N) {
  __shared__ float Wo_s[64 * 32];
  __shared__ float bo_s[32];
  __shared__ float h_s[16 * 64];

  const int tid = threadIdx.x;
  for (int i = tid; i < 2048; i += 256) Wo_s[i] = Wo[i];
  if (tid < 32) bo_s[tid] = bo[tid];

  const int j = tid & 31;
  const int rsub = tid >> 5;
  const int r0 = blockIdx.x * 64;

  for (int g = 0; g < 4; ++g) {
    __syncthreads();
#pragma unroll
    for (int i = 0; i < 4; ++i) {
      int idx = tid + i * 256;
      int rr = idx >> 6;
      int cc = idx & 63;
      int rload = r0 + g * 16 + rr;
      float v = 0.0f;
      if (rload < N) v = fmaxf(h[(size_t)rload * 64 + cc], 0.0f);
      h_s[idx] = v;
    }
    __syncthreads();
#pragma unroll
    for (int rh = 0; rh < 2; ++rh) {
      int rloc = rsub + rh * 8;
      float acc = 0.0f;
#pragma unroll 8
      for (int k = 0; k < 64; ++k)
        acc = fmaf(h_s[rloc * 64 + k], Wo_s[k * 32 + j], acc);
      int r = r0 + g * 16 + rloc;
      if (r < N) out[(size_t)r * 32 + j] = acc + bo_s[j];
    }
  }
}

extern "C" void kernel_launch(void* const* d_in, const int* in_sizes, int n_in,
                              void* d_out, int out_size, void* d_ws, size_t ws_size,
                              hipStream_t stream) {
  const float* x = (const float*)d_in[0];
  const int* ei = (const int*)d_in[1];
  const float* W_in1 = (const float*)d_in[2];
  const float* W_neigh1 = (const float*)d_in[3];
  const float* bias1 = (const float*)d_in[4];
  const float* W_in2 = (const float*)d_in[5];
  const float* W_neigh2 = (const float*)d_in[6];
  const float* bias2 = (const float*)d_in[7];
  const float* W_out = (const float*)d_in[8];
  const float* b_out = (const float*)d_in[9];
  float* out = (float*)d_out;

  const int N = in_sizes[0] / 64;
  const int E = in_sizes[1] / 2;
  const int* row = ei;       // sources
  const int* col = ei + E;   // targets

  // workspace: deg, dinv, indeg, ptr, bsum, csr_row, t(bf16), agg. ~23.2 MB.
  char* ws = (char*)d_ws;
  size_t off = 0;
  auto alloc = [&](size_t bytes) -> void* {
    void* p = ws + off;
    off += (bytes + 255) & ~(size_t)255;
    return p;
  };
  int* deg = (int*)alloc((size_t)N * 4);
  float* dinv = (float*)alloc((size_t)N * 4);
  int* indeg = (int*)alloc((size_t)N * 4);
  int* ptr = (int*)alloc((size_t)N * 4);
  int* bsum = (int*)alloc(256);
  int* csr_row = (int*)alloc((size_t)E * 4);
  __hip_bfloat16* t = (__hip_bfloat16*)alloc((size_t)N * 64 * 2);
  float* agg = (float*)alloc((size_t)N * 64 * 4);
  (void)ws_size;

  hipMemsetAsync(deg, 0, (size_t)N * 4, stream);
  hipMemsetAsync(indeg, 0, (size_t)N * 4, stream);

  int gE = (E + 255) / 256;
  int gN = (N + 255) / 256;
  int gRows = (N + 63) / 64;
  int gNode = (N + 3) / 4;
  int nb = (N + 1023) / 1024;

  k_degrees<<<gE, 256, 0, stream>>>(row, col, deg, indeg, E);
  k_dinv<<<gN, 256, 0, stream>>>(deg, dinv, N);

  // CSR build: ptr = exscan(indeg); bin edges by col.
  k_scan1<<<nb, 1024, 0, stream>>>(indeg, ptr, bsum, N);
  k_scan2<<<1, 64, 0, stream>>>(bsum, nb);
  k_scan3<<<nb, 1024, 0, stream>>>(ptr, bsum, N);
  k_bin<<<gE, 256, 0, stream>>>(row, col, ptr, csr_row, E);

  // layer 1
  k_dual_gemm<false><<<gRows, 256, 0, stream>>>(x, W_neigh1, W_in1, bias1, t, agg, N);
  k_gather<<<gNode, 256, 0, stream>>>(csr_row, ptr, indeg, dinv, t, agg, N);

  // layer 2 (in-place on agg)
  k_dual_gemm<true><<<gRows, 256, 0, stream>>>(agg, W_neigh2, W_in2, bias2, t, agg, N);
  k_gather<<<gNode, 256, 0, stream>>>(csr_row, ptr, indeg, dinv, t, agg, N);

  // output
  k_out_gemm<<<gRows, 256, 0, stream>>>(agg, W_out, b_out, out, N);
}